// Round 2
// baseline (152.493 us; speedup 1.0000x reference)
//
#include <hip/hip_runtime.h>

// Problem constants (fixed by the reference):
//   B=2048, T=200, F=64, H=128, L=1
// Simplifications (exact, not approximations):
//   - L=1 and h=c=0 initially -> W_hh einsum is identically 0; f-gate is dead
//     (it multiplies c_prev==0). W_hh input is provably unused.
//   - Only timestep idx=max(x_len-1,0) per batch row is read out.
// Per row b: i/g/o = W_ih[row]·x[b,idx,:] + b_ih + b_hh,
//   c = sigmoid(i)*tanh(g), h = sigmoid(o)*tanh(c).
// Output: [hs (B*H)] ++ [cs (B*H)], fp32.

namespace {
constexpr int Bc = 2048;
constexpr int Tc = 200;
constexpr int Fc = 64;
constexpr int Hc = 128;
constexpr int TF = Tc * Fc;      // 12800
constexpr int R  = 2;            // batch rows per block
}

// 1024 blocks x 128 threads: thread t owns gate-column j=t, computes R rows.
// No intra-block W duplication; 4 blocks/CU -> 8 waves/CU (2/SIMD).
__global__ __launch_bounds__(128, 2)
void lstm_last_step_kernel(const float* __restrict__ x,     // [B,T,F]
                           const int*   __restrict__ xlen,  // [B]
                           const float* __restrict__ W,     // W_ih [4H, F]
                           const float* __restrict__ b_ih,  // [4H]
                           const float* __restrict__ b_hh,  // [4H]
                           float*       __restrict__ out)   // [2*B*H]
{
  const int j  = threadIdx.x;          // 0..127 gate column
  const int b0 = blockIdx.x * R;

  // ---- Stage the R gathered x rows into LDS first (overlaps W fetch) ----
  __shared__ float xs[R][Fc];          // 512 B
  {
    const int rr = j >> 6;             // 0..1
    const int f  = j & 63;
    const int b  = b0 + rr;
    const int len = xlen[b];
    const int idx = (len == 0) ? 0 : (len - 1);
    xs[rr][f] = x[b * TF + idx * Fc + f];
  }

  // ---- This thread's 3 live W_ih rows (i, g, o) into registers ----
  // Rows: i -> j, g -> 2H+j, o -> 3H+j   (f-row H+j is dead)
  float4 wi[16], wg[16], wo[16];
  const float4* W4 = reinterpret_cast<const float4*>(W);
  #pragma unroll
  for (int q = 0; q < 16; ++q) {
    wi[q] = W4[(0 * Hc + j) * 16 + q];
    wg[q] = W4[(2 * Hc + j) * 16 + q];
    wo[q] = W4[(3 * Hc + j) * 16 + q];
  }
  const float bi = b_ih[0 * Hc + j] + b_hh[0 * Hc + j];
  const float bg = b_ih[2 * Hc + j] + b_hh[2 * Hc + j];
  const float bo = b_ih[3 * Hc + j] + b_hh[3 * Hc + j];

  __syncthreads();

  #pragma unroll
  for (int rr = 0; rr < R; ++rr) {
    const int b = b0 + rr;
    const float4* xv = reinterpret_cast<const float4*>(xs[rr]);

    float ai = bi, ag = bg, ao = bo;
    #pragma unroll
    for (int q = 0; q < 16; ++q) {
      const float4 xq = xv[q];         // wave-uniform LDS address -> broadcast
      ai = fmaf(wi[q].x, xq.x, ai);
      ai = fmaf(wi[q].y, xq.y, ai);
      ai = fmaf(wi[q].z, xq.z, ai);
      ai = fmaf(wi[q].w, xq.w, ai);
      ag = fmaf(wg[q].x, xq.x, ag);
      ag = fmaf(wg[q].y, xq.y, ag);
      ag = fmaf(wg[q].z, xq.z, ag);
      ag = fmaf(wg[q].w, xq.w, ag);
      ao = fmaf(wo[q].x, xq.x, ao);
      ao = fmaf(wo[q].y, xq.y, ao);
      ao = fmaf(wo[q].z, xq.z, ao);
      ao = fmaf(wo[q].w, xq.w, ao);
    }

    const float si = 1.0f / (1.0f + __expf(-ai));
    const float so = 1.0f / (1.0f + __expf(-ao));
    const float tg = tanhf(ag);
    const float c  = si * tg;
    const float h  = so * tanhf(c);

    out[b * Hc + j]           = h;     // hs
    out[Bc * Hc + b * Hc + j] = c;     // cs
  }
}

extern "C" void kernel_launch(void* const* d_in, const int* in_sizes, int n_in,
                              void* d_out, int out_size, void* d_ws, size_t ws_size,
                              hipStream_t stream) {
  // setup_inputs order: encode_features, x_len, W_ih, W_hh, b_ih, b_hh
  const float* x    = (const float*)d_in[0];
  const int*   xlen = (const int*)  d_in[1];
  const float* W_ih = (const float*)d_in[2];
  // d_in[3] = W_hh : provably unused (h_prev == 0)
  const float* b_ih = (const float*)d_in[4];
  const float* b_hh = (const float*)d_in[5];
  float*       out  = (float*)d_out;

  lstm_last_step_kernel<<<Bc / R, 128, 0, stream>>>(x, xlen, W_ih, b_ih, b_hh, out);
}

// Round 3
// 140.565 us; speedup vs baseline: 1.0849x; 1.0849x over previous
//
#include <hip/hip_runtime.h>

// Problem constants (fixed by the reference):
//   B=2048, T=200, F=64, H=128, L=1
// Exact simplifications:
//   - L=1, h=c=0 initially -> W_hh einsum == 0; f-gate dead (multiplies c==0).
//   - Only timestep idx=max(x_len-1,0) per row is read out.
// Per row b: i/g/o = W_ih[row]·x[b,idx,:] + b_ih + b_hh,
//   c = sigmoid(i)*tanh(g), h = sigmoid(o)*tanh(c).
// Output: [hs (B*H)] ++ [cs (B*H)], fp32.
//
// Structure (best measured, R0): 256 blocks x 256 threads, 8 rows/block,
// thread = (j = t&127, r = t>>7). 1 block/CU; W held in 192 VGPRs/thread.

namespace {
constexpr int Bc = 2048;
constexpr int Tc = 200;
constexpr int Fc = 64;
constexpr int Hc = 128;
constexpr int TF = Tc * Fc;          // 12800
constexpr int ROWS_PER_BLOCK = 8;
}

__device__ __forceinline__ float fast_sigmoid(float x) {
  return 1.0f / (1.0f + __expf(-x));
}
__device__ __forceinline__ float fast_tanh(float x) {
  const float ax = __builtin_fabsf(x);
  const float e  = __expf(-2.0f * ax);
  const float t  = (1.0f - e) / (1.0f + e);
  return __builtin_copysignf(t, x);
}

__global__ __launch_bounds__(256, 1)
void lstm_last_step_kernel(const float* __restrict__ x,     // [B,T,F]
                           const int*   __restrict__ xlen,  // [B]
                           const float* __restrict__ W,     // W_ih [4H, F]
                           const float* __restrict__ b_ih,  // [4H]
                           const float* __restrict__ b_hh,  // [4H]
                           float*       __restrict__ out)   // [2*B*H]
{
  const int t  = threadIdx.x;
  const int j  = t & (Hc - 1);       // gate column 0..127
  const int r  = t >> 7;             // 0/1
  const int b0 = blockIdx.x * ROWS_PER_BLOCK;

  // ---- Issue the dependent xlen -> x gather FIRST (hides under W fetch) ----
  __shared__ float xs[ROWS_PER_BLOCK][Fc];   // 2 KB
  {
    // 512 elements staged by 256 threads via float2: thread covers row t>>5,
    // feature pair (t&31)*2.
    const int rr  = t >> 5;          // 0..7
    const int f2  = (t & 31) * 2;    // 0,2,..,62
    const int b   = b0 + rr;
    const int len = xlen[b];
    const int idx = (len == 0) ? 0 : (len - 1);
    const float2 v = *reinterpret_cast<const float2*>(&x[b * TF + idx * Fc + f2]);
    *reinterpret_cast<float2*>(&xs[rr][f2]) = v;
  }

  // ---- 3 live W_ih rows (i, g, o) into registers (f-row H+j is dead) ----
  float4 wi[16], wg[16], wo[16];
  const float4* W4 = reinterpret_cast<const float4*>(W);
  #pragma unroll
  for (int q = 0; q < 16; ++q) {
    wi[q] = W4[(0 * Hc + j) * 16 + q];
    wg[q] = W4[(2 * Hc + j) * 16 + q];
    wo[q] = W4[(3 * Hc + j) * 16 + q];
  }
  const float bi = b_ih[0 * Hc + j] + b_hh[0 * Hc + j];
  const float bg = b_ih[2 * Hc + j] + b_hh[2 * Hc + j];
  const float bo = b_ih[3 * Hc + j] + b_hh[3 * Hc + j];

  __syncthreads();

  #pragma unroll
  for (int p = 0; p < 4; ++p) {
    const int rowlocal = p * 2 + r;            // wave-uniform
    const int b = b0 + rowlocal;
    const float4* xv = reinterpret_cast<const float4*>(xs[rowlocal]);

    float ai = bi, ag = bg, ao = bo;
    #pragma unroll
    for (int q = 0; q < 16; ++q) {
      const float4 xq = xv[q];                 // wave-uniform LDS broadcast
      ai = fmaf(wi[q].x, xq.x, ai);
      ai = fmaf(wi[q].y, xq.y, ai);
      ai = fmaf(wi[q].z, xq.z, ai);
      ai = fmaf(wi[q].w, xq.w, ai);
      ag = fmaf(wg[q].x, xq.x, ag);
      ag = fmaf(wg[q].y, xq.y, ag);
      ag = fmaf(wg[q].z, xq.z, ag);
      ag = fmaf(wg[q].w, xq.w, ag);
      ao = fmaf(wo[q].x, xq.x, ao);
      ao = fmaf(wo[q].y, xq.y, ao);
      ao = fmaf(wo[q].z, xq.z, ao);
      ao = fmaf(wo[q].w, xq.w, ao);
    }

    const float c = fast_sigmoid(ai) * fast_tanh(ag);
    const float h = fast_sigmoid(ao) * fast_tanh(c);

    __builtin_nontemporal_store(h, &out[b * Hc + j]);            // hs
    __builtin_nontemporal_store(c, &out[Bc * Hc + b * Hc + j]);  // cs
  }
}

extern "C" void kernel_launch(void* const* d_in, const int* in_sizes, int n_in,
                              void* d_out, int out_size, void* d_ws, size_t ws_size,
                              hipStream_t stream) {
  // setup_inputs order: encode_features, x_len, W_ih, W_hh, b_ih, b_hh
  const float* x    = (const float*)d_in[0];
  const int*   xlen = (const int*)  d_in[1];
  const float* W_ih = (const float*)d_in[2];
  // d_in[3] = W_hh : provably unused (h_prev == 0)
  const float* b_ih = (const float*)d_in[4];
  const float* b_hh = (const float*)d_in[5];
  float*       out  = (float*)d_out;

  lstm_last_step_kernel<<<Bc / ROWS_PER_BLOCK, 256, 0, stream>>>(
      x, xlen, W_ih, b_ih, b_hh, out);
}